// Round 1
// baseline (108.892 us; speedup 1.0000x reference)
//
#include <hip/hip_runtime.h>
#include <hip/hip_bf16.h>
#include <stdint.h>

// Recommender: B=4096 users, L=200 history, D=64 emb, F=100000 films.
// Kernel 1 (one block per user): masked mean rating -> weights -> gather emb
// rows, accumulate min/max/sum per dim, stage 16-bit sortable keys in LDS,
// bit-serial radix-select the median per dim (4 lanes per dim), L2-normalize
// ue(256), write x = [ue, fe] (B x 320) to workspace.
// Kernel 2: tiny MLP 320->128->64->1 + sigmoid, 8 users per block, f32 VALU.

#define B_ 4096
#define L_ 200
#define D_ 64
#define PITCH_DW 106            // dwords per key row (even for b64 align; 106%32=10 -> <=4-way banks)
#define PITCH_U16 (PITCH_DW*2)

__global__ __launch_bounds__(256) void user_emb_kernel(
    const int* __restrict__ film_hist,
    const float* __restrict__ ratings,
    const int* __restrict__ lengths,
    const int* __restrict__ film_indices,
    const float* __restrict__ emb,
    float* __restrict__ x)
{
  __shared__ uint32_t keys[D_ * PITCH_DW];   // 27136 B, u16 keys packed 2/dword
  __shared__ int   hist_s[L_];
  __shared__ float rat_s[L_];
  __shared__ float pmin[4*D_], pmax[4*D_], psum[4*D_];
  __shared__ float ue[4*D_];                 // [min|max|mean|med]
  __shared__ float red[4];

  const int b = blockIdx.x;
  const int t = threadIdx.x;
  const int wave = t >> 6;
  const int lane = t & 63;
  const int n = lengths[b];

  // stage history + ratings; film embedding written straight to x
  float r = 0.f;
  if (t < n) {
    int h = film_hist[(size_t)b*L_ + t];
    float rv = ratings[(size_t)b*L_ + t];
    hist_s[t] = h; rat_s[t] = rv; r = rv;
  }
  if (t >= 64 && t < 128) {
    int fi = film_indices[b];
    x[(size_t)b*320 + 256 + (t-64)] = emb[(size_t)fi*D_ + (t-64)];
  }

  // mean rating (block reduce over 256 lanes; t>=n contribute 0)
  float s = r;
  #pragma unroll
  for (int off = 32; off; off >>= 1) s += __shfl_down(s, off);
  if (lane == 0) red[wave] = s;
  __syncthreads();
  const float mean_r = (red[0]+red[1]+red[2]+red[3]) / (float)n;

  // phase 1: gather rows (wave w handles l = w, w+4, ...), lane = dim
  float vmin = __builtin_inff(), vmax = -__builtin_inff(), vsum = 0.f;
  #pragma unroll 2
  for (int l = wave; l < n; l += 4) {
    const int h = hist_s[l];
    const float wgt = rat_s[l] - mean_r + 0.1f;
    const float w = emb[(size_t)h*D_ + lane] * wgt;
    vmin = fminf(vmin, w); vmax = fmaxf(vmax, w); vsum += w;
    uint32_t u = __float_as_uint(w);
    uint32_t key = u ^ (0x80000000u | (uint32_t)((int32_t)u >> 31)); // sortable
    ((uint16_t*)keys)[lane*PITCH_U16 + l] = (uint16_t)(key >> 16);   // truncate to 16b
  }
  pmin[wave*D_+lane] = vmin; pmax[wave*D_+lane] = vmax; psum[wave*D_+lane] = vsum;

  // sentinel-pad keys up to multiple of 16 (covers b64-strided reads)
  const int n_pad = (n + 15) & ~15;
  for (int idx = t; idx < D_*(n_pad - n); idx += 256) {
    int d2 = idx & 63, lo = n + (idx >> 6);
    ((uint16_t*)keys)[d2*PITCH_U16 + lo] = 0xFFFFu;
  }
  __syncthreads();

  if (t < D_) {
    float mn = fminf(fminf(pmin[t], pmin[64+t]), fminf(pmin[128+t], pmin[192+t]));
    float mx = fmaxf(fmaxf(pmax[t], pmax[64+t]), fmaxf(pmax[128+t], pmax[192+t]));
    float sm = psum[t] + psum[64+t] + psum[128+t] + psum[192+t];
    ue[t] = mn; ue[64+t] = mx; ue[128+t] = sm / (float)n;
  }

  // phase 2: bit-serial radix select of k-th smallest 16-bit key.
  // 4 lanes per dim (dim = t>>2, sub = t&3); monotone truncation commutes
  // with order statistics, so prefix == trunc(true median).
  const int d = t >> 2, sub = t & 3;
  const uint32_t* row = keys + d * PITCH_DW;
  int k = (n - 1) >> 1;
  uint32_t prefix = 0;
  const int iters = n_pad >> 4;      // 16 keys (= 2 dwords x 4 subs) per iter
  for (int bit = 15; bit >= 0; --bit) {
    const uint32_t target = prefix >> bit;
    int cnt = 0;
    for (int i = 0; i < iters; ++i) {
      uint2 v = *(const uint2*)(row + 2*sub + 8*i);
      cnt += (int)(((v.x & 0xFFFFu) >> bit) == target);
      cnt += (int)((v.x >> (16 + bit)) == target);
      cnt += (int)(((v.y & 0xFFFFu) >> bit) == target);
      cnt += (int)((v.y >> (16 + bit)) == target);
    }
    cnt += __shfl_xor(cnt, 1);
    cnt += __shfl_xor(cnt, 2);
    if (k >= cnt) { k -= cnt; prefix |= (1u << bit); }
  }
  if (sub == 0) {
    uint32_t key32 = (prefix << 16) | 0x8000u;  // bucket midpoint
    float med = (prefix & 0x8000u) ? __uint_as_float(key32 ^ 0x80000000u)
                                   : __uint_as_float(~key32);
    ue[192 + d] = med;
  }
  __syncthreads();

  // L2-normalize ue and write x[b, 0:256]
  float v = ue[t];
  float ss = v*v;
  #pragma unroll
  for (int off = 32; off; off >>= 1) ss += __shfl_down(ss, off);
  if (lane == 0) red[wave] = ss;
  __syncthreads();
  const float rn = 1.0f / sqrtf(red[0]+red[1]+red[2]+red[3]);
  x[(size_t)b*320 + t] = v * rn;
}

#define U_ 8   // users per MLP block -> 512 blocks

__global__ __launch_bounds__(256) void mlp_kernel(
    const float* __restrict__ x,
    const float* __restrict__ W1, const float* __restrict__ b1,
    const float* __restrict__ W2, const float* __restrict__ b2,
    const float* __restrict__ W3, const float* __restrict__ b3,
    float* __restrict__ out)
{
  __shared__ float xs[U_*320];
  __shared__ float h1s[U_*128];
  __shared__ float h2s[U_*64];
  const int t = threadIdx.x;
  const int u0 = blockIdx.x * U_;

  for (int i = t; i < U_*320/4; i += 256)
    ((float4*)xs)[i] = ((const float4*)(x + (size_t)u0*320))[i];
  __syncthreads();

  // h1 = relu(x @ W1 + b1): 8 users x 128 out; thread = (j, 4-user group)
  {
    const int j = t & 127, g = t >> 7;
    const int ub = g*4;
    float acc[4];
    const float bj = b1[j];
    #pragma unroll
    for (int q = 0; q < 4; ++q) acc[q] = bj;
    for (int i = 0; i < 320; i += 4) {
      float w0 = W1[(i+0)*128 + j];
      float w1 = W1[(i+1)*128 + j];
      float w2 = W1[(i+2)*128 + j];
      float w3 = W1[(i+3)*128 + j];
      #pragma unroll
      for (int q = 0; q < 4; ++q) {
        float4 xv = *(const float4*)&xs[(ub+q)*320 + i];   // LDS broadcast in-wave
        acc[q] += xv.x*w0 + xv.y*w1 + xv.z*w2 + xv.w*w3;
      }
    }
    #pragma unroll
    for (int q = 0; q < 4; ++q) h1s[(ub+q)*128 + j] = fmaxf(acc[q], 0.f);
  }
  __syncthreads();

  // h2 = relu(h1 @ W2 + b2): 8 users x 64 out
  {
    const int j = t & 63, g = t >> 6;
    const int ub = g*2;
    float acc[2];
    const float bj = b2[j];
    acc[0] = bj; acc[1] = bj;
    for (int i = 0; i < 128; i += 4) {
      float w0 = W2[(i+0)*64 + j];
      float w1 = W2[(i+1)*64 + j];
      float w2 = W2[(i+2)*64 + j];
      float w3 = W2[(i+3)*64 + j];
      #pragma unroll
      for (int q = 0; q < 2; ++q) {
        float4 hv = *(const float4*)&h1s[(ub+q)*128 + i];
        acc[q] += hv.x*w0 + hv.y*w1 + hv.z*w2 + hv.w*w3;
      }
    }
    #pragma unroll
    for (int q = 0; q < 2; ++q) h2s[(ub+q)*64 + j] = fmaxf(acc[q], 0.f);
  }
  __syncthreads();

  // out = sigmoid(h2 @ W3 + b3)
  if (t < U_*4) {
    const int u = t >> 2, sub = t & 3;
    float a = 0.f;
    #pragma unroll
    for (int i = 0; i < 16; ++i) a += h2s[u*64 + sub*16 + i] * W3[sub*16 + i];
    a += __shfl_xor(a, 1);
    a += __shfl_xor(a, 2);
    if (sub == 0) out[u0 + u] = 1.f / (1.f + __expf(-(a + b3[0])));
  }
}

extern "C" void kernel_launch(void* const* d_in, const int* in_sizes, int n_in,
                              void* d_out, int out_size, void* d_ws, size_t ws_size,
                              hipStream_t stream) {
  const int*   film_hist = (const int*)d_in[0];
  const float* ratings   = (const float*)d_in[1];
  const int*   lengths   = (const int*)d_in[2];
  const int*   film_idx  = (const int*)d_in[3];
  const float* emb       = (const float*)d_in[4];
  const float* W1 = (const float*)d_in[5];
  const float* b1 = (const float*)d_in[6];
  const float* W2 = (const float*)d_in[7];
  const float* b2 = (const float*)d_in[8];
  const float* W3 = (const float*)d_in[9];
  const float* b3 = (const float*)d_in[10];

  float* xbuf = (float*)d_ws;                 // B*320 f32 = 5.24 MB
  float* outp = (float*)d_out;

  user_emb_kernel<<<B_, 256, 0, stream>>>(film_hist, ratings, lengths, film_idx, emb, xbuf);
  mlp_kernel<<<B_/U_, 256, 0, stream>>>(xbuf, W1, b1, W2, b2, W3, b3, outp);
}

// Round 2
// 85.300 us; speedup vs baseline: 1.2766x; 1.2766x over previous
//
#include <hip/hip_runtime.h>
#include <hip/hip_bf16.h>
#include <stdint.h>

// Recommender: B=4096 users, L=200 history, D=64 emb, F=100000 films.
// Kernel 1 (one 512-thread block per user): masked mean rating -> weights ->
// gather emb (8 lanes per dim, 32B segments), accumulate min/max/sum in
// registers, build 16 bit-plane registers of the 16-bit sortable key, then
// bit-serial radix-select the median with popcount+shuffles (no LDS keys).
// L2-normalize ue(256), write x = [ue, fe] (B x 320) to workspace.
// Kernel 2: tiny MLP 320->128->64->1 + sigmoid, 8 users per block, f32 VALU.

#define B_ 4096
#define L_ 200
#define D_ 64

__global__ __launch_bounds__(512) void user_emb_kernel(
    const int* __restrict__ film_hist,
    const float* __restrict__ ratings,
    const int* __restrict__ lengths,
    const int* __restrict__ film_indices,
    const float* __restrict__ emb,
    float* __restrict__ x)
{
  __shared__ int   hist_s[L_];
  __shared__ float rat_s[L_];
  __shared__ float red[8];
  __shared__ float ue[4*D_];                 // [min|max|mean|med]

  const int b = blockIdx.x;
  const int t = threadIdx.x;
  const int wave = t >> 6;
  const int lane = t & 63;
  const int sub  = lane >> 3;                // 0..7  (key subset)
  const int dloc = lane & 7;
  const int d    = wave * 8 + dloc;          // 0..63 (dim)
  const int n = lengths[b];

  // stage history + ratings; film embedding written straight to x
  float r = 0.f;
  if (t < n) {
    hist_s[t] = film_hist[(size_t)b*L_ + t];
    float rv = ratings[(size_t)b*L_ + t];
    rat_s[t] = rv; r = rv;
  }
  if (t >= 448) {
    int fi = film_indices[b];
    x[(size_t)b*320 + 256 + (t-448)] = emb[(size_t)fi*D_ + (t-448)];
  }

  // mean rating (block reduce; t>=n contribute 0)
  float s = r;
  #pragma unroll
  for (int off = 32; off; off >>= 1) s += __shfl_down(s, off);
  if (lane == 0) red[wave] = s;
  __syncthreads();
  const float mean_r = (red[0]+red[1]+red[2]+red[3]+red[4]+red[5]+red[6]+red[7]) / (float)n;

  // phase 1: gather + stats + bit-plane build.
  // lane (sub,dloc) of wave w handles keys l = sub, sub+8, ... for dim d.
  float vmin = __builtin_inff(), vmax = -__builtin_inff(), vsum = 0.f;
  uint32_t P[16];
  #pragma unroll
  for (int i = 0; i < 16; ++i) P[i] = 0u;

  const int c = (n - sub + 7) >> 3;          // keys owned by this lane (<=25)
  const float* embd = emb + d;
  for (int i = 0; i < c; ++i) {
    const int l = sub + 8*i;
    const int h = hist_s[l];
    const float wgt = rat_s[l] - mean_r + 0.1f;
    const float w = embd[(size_t)h * D_] * wgt;
    vmin = fminf(vmin, w); vmax = fmaxf(vmax, w); vsum += w;
    uint32_t u = __float_as_uint(w);
    uint32_t key = (u ^ (0x80000000u | (uint32_t)((int32_t)u >> 31))) >> 16; // sortable, 16b
    #pragma unroll
    for (int bb = 0; bb < 16; ++bb) {
      uint32_t bitv = (key >> bb) & 1u;
      P[bb] = __builtin_amdgcn_alignbit(bitv, P[bb], 1);  // shift-in from top
    }
  }

  // combine min/max/sum across the 8 subs (lane bits 3,4,5)
  vmin = fminf(vmin, __shfl_xor(vmin, 8));
  vmin = fminf(vmin, __shfl_xor(vmin, 16));
  vmin = fminf(vmin, __shfl_xor(vmin, 32));
  vmax = fmaxf(vmax, __shfl_xor(vmax, 8));
  vmax = fmaxf(vmax, __shfl_xor(vmax, 16));
  vmax = fmaxf(vmax, __shfl_xor(vmax, 32));
  vsum += __shfl_xor(vsum, 8);
  vsum += __shfl_xor(vsum, 16);
  vsum += __shfl_xor(vsum, 32);

  // phase 2: bit-serial select of k-th smallest key, zero memory traffic.
  uint32_t alive = (c > 0) ? (0xFFFFFFFFu << (32 - c)) : 0u;
  int k = (n - 1) >> 1;
  uint32_t prefix = 0;
  #pragma unroll
  for (int bb = 15; bb >= 0; --bb) {
    uint32_t z = alive & ~P[bb];
    int cnt = __popc(z);
    cnt += __shfl_xor(cnt, 8);
    cnt += __shfl_xor(cnt, 16);
    cnt += __shfl_xor(cnt, 32);
    const bool zero_side = (k < cnt);
    alive  = zero_side ? z : (alive & P[bb]);
    k      = zero_side ? k : (k - cnt);
    prefix = zero_side ? prefix : (prefix | (1u << bb));
  }

  if (sub == 0) {
    uint32_t key32 = (prefix << 16) | 0x8000u;  // bucket midpoint
    float med = (prefix & 0x8000u) ? __uint_as_float(key32 ^ 0x80000000u)
                                   : __uint_as_float(~key32);
    ue[d]      = vmin;
    ue[64 + d] = vmax;
    ue[128+ d] = vsum / (float)n;
    ue[192+ d] = med;
  }
  __syncthreads();

  // L2-normalize ue and write x[b, 0:256]
  float v = (t < 256) ? ue[t] : 0.f;
  float ss = v*v;
  #pragma unroll
  for (int off = 32; off; off >>= 1) ss += __shfl_down(ss, off);
  if (lane == 0) red[wave] = ss;
  __syncthreads();
  const float rn = 1.0f / sqrtf(red[0]+red[1]+red[2]+red[3]+red[4]+red[5]+red[6]+red[7]);
  if (t < 256) x[(size_t)b*320 + t] = v * rn;
}

#define U_ 8   // users per MLP block -> 512 blocks

__global__ __launch_bounds__(256) void mlp_kernel(
    const float* __restrict__ x,
    const float* __restrict__ W1, const float* __restrict__ b1,
    const float* __restrict__ W2, const float* __restrict__ b2,
    const float* __restrict__ W3, const float* __restrict__ b3,
    float* __restrict__ out)
{
  __shared__ float xs[U_*320];
  __shared__ float h1s[U_*128];
  __shared__ float h2s[U_*64];
  const int t = threadIdx.x;
  const int u0 = blockIdx.x * U_;

  for (int i = t; i < U_*320/4; i += 256)
    ((float4*)xs)[i] = ((const float4*)(x + (size_t)u0*320))[i];
  __syncthreads();

  // h1 = relu(x @ W1 + b1): 8 users x 128 out; thread = (j, 4-user group)
  {
    const int j = t & 127, g = t >> 7;
    const int ub = g*4;
    float acc[4];
    const float bj = b1[j];
    #pragma unroll
    for (int q = 0; q < 4; ++q) acc[q] = bj;
    for (int i = 0; i < 320; i += 4) {
      float w0 = W1[(i+0)*128 + j];
      float w1 = W1[(i+1)*128 + j];
      float w2 = W1[(i+2)*128 + j];
      float w3 = W1[(i+3)*128 + j];
      #pragma unroll
      for (int q = 0; q < 4; ++q) {
        float4 xv = *(const float4*)&xs[(ub+q)*320 + i];   // LDS broadcast in-wave
        acc[q] += xv.x*w0 + xv.y*w1 + xv.z*w2 + xv.w*w3;
      }
    }
    #pragma unroll
    for (int q = 0; q < 4; ++q) h1s[(ub+q)*128 + j] = fmaxf(acc[q], 0.f);
  }
  __syncthreads();

  // h2 = relu(h1 @ W2 + b2): 8 users x 64 out
  {
    const int j = t & 63, g = t >> 6;
    const int ub = g*2;
    float acc[2];
    const float bj = b2[j];
    acc[0] = bj; acc[1] = bj;
    for (int i = 0; i < 128; i += 4) {
      float w0 = W2[(i+0)*64 + j];
      float w1 = W2[(i+1)*64 + j];
      float w2 = W2[(i+2)*64 + j];
      float w3 = W2[(i+3)*64 + j];
      #pragma unroll
      for (int q = 0; q < 2; ++q) {
        float4 hv = *(const float4*)&h1s[(ub+q)*128 + i];
        acc[q] += hv.x*w0 + hv.y*w1 + hv.z*w2 + hv.w*w3;
      }
    }
    #pragma unroll
    for (int q = 0; q < 2; ++q) h2s[(ub+q)*64 + j] = fmaxf(acc[q], 0.f);
  }
  __syncthreads();

  // out = sigmoid(h2 @ W3 + b3)
  if (t < U_*4) {
    const int u = t >> 2, sub = t & 3;
    float a = 0.f;
    #pragma unroll
    for (int i = 0; i < 16; ++i) a += h2s[u*64 + sub*16 + i] * W3[sub*16 + i];
    a += __shfl_xor(a, 1);
    a += __shfl_xor(a, 2);
    if (sub == 0) out[u0 + u] = 1.f / (1.f + __expf(-(a + b3[0])));
  }
}

extern "C" void kernel_launch(void* const* d_in, const int* in_sizes, int n_in,
                              void* d_out, int out_size, void* d_ws, size_t ws_size,
                              hipStream_t stream) {
  const int*   film_hist = (const int*)d_in[0];
  const float* ratings   = (const float*)d_in[1];
  const int*   lengths   = (const int*)d_in[2];
  const int*   film_idx  = (const int*)d_in[3];
  const float* emb       = (const float*)d_in[4];
  const float* W1 = (const float*)d_in[5];
  const float* b1 = (const float*)d_in[6];
  const float* W2 = (const float*)d_in[7];
  const float* b2 = (const float*)d_in[8];
  const float* W3 = (const float*)d_in[9];
  const float* b3 = (const float*)d_in[10];

  float* xbuf = (float*)d_ws;                 // B*320 f32 = 5.24 MB
  float* outp = (float*)d_out;

  user_emb_kernel<<<B_, 512, 0, stream>>>(film_hist, ratings, lengths, film_idx, emb, xbuf);
  mlp_kernel<<<B_/U_, 256, 0, stream>>>(xbuf, W1, b1, W2, b2, W3, b3, outp);
}